// Round 1
// baseline (399.340 us; speedup 1.0000x reference)
//
#include <hip/hip_runtime.h>
#include <hip/hip_bf16.h>
#include <math.h>

#define D 1024
#define S 8192
#define B 8
#define H 16
#define NROWS (B * S)
#define EPS_LN 1e-5f

// ---------- helpers ----------
__device__ __forceinline__ float wred_sum(float v) {
#pragma unroll
  for (int m = 1; m < 64; m <<= 1) v += __shfl_xor(v, m, 64);
  return v;
}
__device__ __forceinline__ float wred_max(float v) {
#pragma unroll
  for (int m = 1; m < 64; m <<= 1) v = fmaxf(v, __shfl_xor(v, m, 64));
  return v;
}
__device__ __forceinline__ unsigned short f32_to_bf16(float f) {
  unsigned int u = __float_as_uint(f);
  u += 0x7fffu + ((u >> 16) & 1u);  // RNE
  return (unsigned short)(u >> 16);
}

// ---------- LN over one 1024-row per block (256 thr) ----------
__global__ void k_ln256(const float* __restrict__ in, const float* __restrict__ g,
                        const float* __restrict__ bb, float* __restrict__ out) {
  const int b = blockIdx.x, t = threadIdx.x;
  float4 v = ((const float4*)(in + (size_t)b * D))[t];
  float s = v.x + v.y + v.z + v.w;
  float s2 = fmaf(v.x, v.x, fmaf(v.y, v.y, fmaf(v.z, v.z, v.w * v.w)));
  __shared__ float red[8];
  float ws = wred_sum(s), ws2 = wred_sum(s2);
  const int lane = t & 63, wv = t >> 6;
  if (!lane) { red[wv] = ws; red[wv + 4] = ws2; }
  __syncthreads();
  ws = red[0] + red[1] + red[2] + red[3];
  ws2 = red[4] + red[5] + red[6] + red[7];
  const float m = ws * (1.f / D);
  const float rs = rsqrtf(ws2 * (1.f / D) - m * m + EPS_LN);
  const float4 gg = ((const float4*)g)[t], bv = ((const float4*)bb)[t];
  float4 o;
  o.x = (v.x - m) * rs * gg.x + bv.x;
  o.y = (v.y - m) * rs * gg.y + bv.y;
  o.z = (v.z - m) * rs * gg.z + bv.z;
  o.w = (v.w - m) * rs * gg.w + bv.w;
  ((float4*)(out + (size_t)b * D))[t] = o;
}

// ---------- q[j] = qn . Wq[j,:] + bq[j] : one wave per j ----------
__global__ void k_qproj(const float* __restrict__ qn, const float* __restrict__ Wq,
                        const float* __restrict__ bq, float* __restrict__ q) {
  const int wv = threadIdx.x >> 6, lane = threadIdx.x & 63;
  const int j = blockIdx.x * 4 + wv;
  const float4* wr = (const float4*)(Wq + (size_t)j * D);
  const float4* qr = (const float4*)qn;
  float acc = 0.f;
#pragma unroll
  for (int k = 0; k < 4; k++) {
    float4 a = qr[lane + 64 * k], w = wr[lane + 64 * k];
    acc = fmaf(a.x, w.x, acc); acc = fmaf(a.y, w.y, acc);
    acc = fmaf(a.z, w.z, acc); acc = fmaf(a.w, w.w, acc);
  }
  acc = wred_sum(acc);
  if (!lane) q[j] = acc + bq[j];
}

// ---------- U[h][d] = scale * sum_e q[h*64+e] * Wk[h*64+e][d]  (bf16 out) ----------
__global__ void k_uproj(const float* __restrict__ q, const float* __restrict__ Wk,
                        unsigned short* __restrict__ U) {
  const int idx = blockIdx.x * 256 + threadIdx.x;
  const int h = idx >> 10, d = idx & (D - 1);
  float acc = 0.f;
#pragma unroll 4
  for (int e = 0; e < 64; e++)
    acc = fmaf(q[h * 64 + e], Wk[(size_t)(h * 64 + e) * D + d], acc);
  U[idx] = f32_to_bf16(acc * 0.125f);  // 1/sqrt(64)
}

// ---------- pass 1 over x: LN stats + scores (one wave per row) ----------
__global__ __launch_bounds__(256) void k_scores(
    const float* __restrict__ x, const unsigned short* __restrict__ Ug,
    const float* __restrict__ g1, const float* __restrict__ b1,
    const float* __restrict__ kg, const float* __restrict__ kb,
    float* __restrict__ stats, float* __restrict__ sc) {
  __shared__ unsigned short sU[H * D];  // 32 KB
  for (int i = threadIdx.x; i < H * D / 8; i += 256)
    ((uint4*)sU)[i] = ((const uint4*)Ug)[i];
  __syncthreads();
  const int lane = threadIdx.x & 63, wv = threadIdx.x >> 6;
  for (int r = blockIdx.x * 4 + wv; r < NROWS; r += gridDim.x * 4) {
    const float4* xr = (const float4*)(x + (size_t)r * D);
    float4 xv[4];
#pragma unroll
    for (int k = 0; k < 4; k++) xv[k] = xr[lane + 64 * k];
    float s = 0.f, s2 = 0.f;
#pragma unroll
    for (int k = 0; k < 4; k++) {
      s += xv[k].x + xv[k].y + xv[k].z + xv[k].w;
      s2 = fmaf(xv[k].x, xv[k].x, s2); s2 = fmaf(xv[k].y, xv[k].y, s2);
      s2 = fmaf(xv[k].z, xv[k].z, s2); s2 = fmaf(xv[k].w, xv[k].w, s2);
    }
    s = wred_sum(s); s2 = wred_sum(s2);
    const float m1 = s * (1.f / D);
    const float rs1 = rsqrtf(s2 * (1.f / D) - m1 * m1 + EPS_LN);
    // xn = (x - m1)*rs1*g + b
#pragma unroll
    for (int k = 0; k < 4; k++) {
      float4 gv = ((const float4*)g1)[lane + 64 * k];
      float4 bv = ((const float4*)b1)[lane + 64 * k];
      xv[k].x = (xv[k].x - m1) * rs1 * gv.x + bv.x;
      xv[k].y = (xv[k].y - m1) * rs1 * gv.y + bv.y;
      xv[k].z = (xv[k].z - m1) * rs1 * gv.z + bv.z;
      xv[k].w = (xv[k].w - m1) * rs1 * gv.w + bv.w;
    }
    s = 0.f; s2 = 0.f;
#pragma unroll
    for (int k = 0; k < 4; k++) {
      s += xv[k].x + xv[k].y + xv[k].z + xv[k].w;
      s2 = fmaf(xv[k].x, xv[k].x, s2); s2 = fmaf(xv[k].y, xv[k].y, s2);
      s2 = fmaf(xv[k].z, xv[k].z, s2); s2 = fmaf(xv[k].w, xv[k].w, s2);
    }
    s = wred_sum(s); s2 = wred_sum(s2);
    const float m2 = s * (1.f / D);
    const float rs2 = rsqrtf(s2 * (1.f / D) - m2 * m2 + EPS_LN);
    if (!lane) ((float4*)stats)[r] = make_float4(m1, rs1, m2, rs2);
    // kn = (xn - m2)*rs2*kg + kb
#pragma unroll
    for (int k = 0; k < 4; k++) {
      float4 gv = ((const float4*)kg)[lane + 64 * k];
      float4 bv = ((const float4*)kb)[lane + 64 * k];
      xv[k].x = (xv[k].x - m2) * rs2 * gv.x + bv.x;
      xv[k].y = (xv[k].y - m2) * rs2 * gv.y + bv.y;
      xv[k].z = (xv[k].z - m2) * rs2 * gv.z + bv.z;
      xv[k].w = (xv[k].w - m2) * rs2 * gv.w + bv.w;
    }
    float p[16];
#pragma unroll
    for (int h = 0; h < 16; h++) p[h] = 0.f;
#pragma unroll
    for (int k = 0; k < 4; k++) {
#pragma unroll
      for (int h = 0; h < 16; h++) {
        // 4 consecutive bf16 of U[h] at d0 = 4*lane + 256*k  -> conflict-free ds_read_b64
        uint2 u = ((const uint2*)sU)[h * 256 + lane + 64 * k];
        float u0 = __uint_as_float((u.x & 0xffffu) << 16);
        float u1 = __uint_as_float(u.x & 0xffff0000u);
        float u2 = __uint_as_float((u.y & 0xffffu) << 16);
        float u3 = __uint_as_float(u.y & 0xffff0000u);
        p[h] = fmaf(u0, xv[k].x, p[h]); p[h] = fmaf(u1, xv[k].y, p[h]);
        p[h] = fmaf(u2, xv[k].z, p[h]); p[h] = fmaf(u3, xv[k].w, p[h]);
      }
    }
#pragma unroll
    for (int h = 0; h < 16; h++) p[h] = wred_sum(p[h]);
    if (!lane) {
      float4* o = (float4*)(sc + (size_t)r * 16);
      o[0] = make_float4(p[0], p[1], p[2], p[3]);
      o[1] = make_float4(p[4], p[5], p[6], p[7]);
      o[2] = make_float4(p[8], p[9], p[10], p[11]);
      o[3] = make_float4(p[12], p[13], p[14], p[15]);
    }
  }
}

// ---------- softmax over S per (b,h), in place ----------
__global__ void k_softmax(float* __restrict__ sc) {
  const int b = blockIdx.x >> 4, h = blockIdx.x & 15;
  float* base = sc + (size_t)b * S * 16 + h;
  const int t = threadIdx.x, lane = t & 63, wv = t >> 6;
  __shared__ float redA[4], redB[4];
  float vals[32];
  float mx = -3.4e38f;
#pragma unroll
  for (int i = 0; i < 32; i++) {
    vals[i] = base[(size_t)(t + 256 * i) * 16];
    mx = fmaxf(mx, vals[i]);
  }
  mx = wred_max(mx);
  if (!lane) redA[wv] = mx;
  __syncthreads();
  mx = fmaxf(fmaxf(redA[0], redA[1]), fmaxf(redA[2], redA[3]));
  float sum = 0.f;
#pragma unroll
  for (int i = 0; i < 32; i++) {
    vals[i] = expf(vals[i] - mx);
    sum += vals[i];
  }
  sum = wred_sum(sum);
  if (!lane) redB[wv] = sum;
  __syncthreads();
  const float tot = redB[0] + redB[1] + redB[2] + redB[3];
  const float inv = 1.f / (tot + 1e-9f);
#pragma unroll
  for (int i = 0; i < 32; i++) {
    float a = vals[i] * inv;
    a = fminf(fmaxf(a, 1e-9f), 1.f);
    base[(size_t)(t + 256 * i) * 16] = a;
  }
}

// ---------- pass 2 over x: vn recompute + attn-weighted column accumulate ----------
__global__ __launch_bounds__(512) void k_accv(
    const float* __restrict__ x, const float* __restrict__ stats,
    const float* __restrict__ attn,
    const float* __restrict__ g1, const float* __restrict__ b1,
    const float* __restrict__ vg, const float* __restrict__ vb,
    float* __restrict__ part, int CH, int RPC) {
  const int b = blockIdx.x / CH, ch = blockIdx.x % CH;
  const int c0 = threadIdx.x * 2;
  const float2 gv = *(const float2*)(g1 + c0), bv = *(const float2*)(b1 + c0);
  const float2 vgv = *(const float2*)(vg + c0), vbv = *(const float2*)(vb + c0);
  float acc0[16], acc1[16];
#pragma unroll
  for (int h = 0; h < 16; h++) { acc0[h] = 0.f; acc1[h] = 0.f; }
  const int r0 = b * S + ch * RPC;
  for (int i = 0; i < RPC; i++) {
    const int r = r0 + i;
    const float4 st = ((const float4*)stats)[r];  // m1 rs1 m2 rs2
    const float2 xv = *(const float2*)(x + (size_t)r * D + c0);
    float xn0 = (xv.x - st.x) * st.y * gv.x + bv.x;
    float xn1 = (xv.y - st.x) * st.y * gv.y + bv.y;
    const float v0 = (xn0 - st.z) * st.w * vgv.x + vbv.x;
    const float v1 = (xn1 - st.z) * st.w * vgv.y + vbv.y;
    const float* w = attn + (size_t)r * 16;
#pragma unroll
    for (int h = 0; h < 16; h++) {
      const float wh = w[h];
      acc0[h] = fmaf(wh, v0, acc0[h]);
      acc1[h] = fmaf(wh, v1, acc1[h]);
    }
  }
  float* po = part + (size_t)blockIdx.x * (H * D);
#pragma unroll
  for (int h = 0; h < 16; h++)
    *(float2*)(po + h * D + c0) = make_float2(acc0[h], acc1[h]);
}

// ---------- reduce chunk partials -> wsum[b][h][d] ----------
__global__ void k_redpart(const float* __restrict__ part, float* __restrict__ wsum,
                          int CH) {
  const int b = blockIdx.x >> 4, h = blockIdx.x & 15;
  const int d = threadIdx.x * 4;
  float4 a = make_float4(0.f, 0.f, 0.f, 0.f);
  for (int k = 0; k < CH; k++) {
    const float4 p = *(const float4*)(part + ((size_t)(b * CH + k) * H + h) * D + d);
    a.x += p.x; a.y += p.y; a.z += p.z; a.w += p.w;
  }
  *(float4*)(wsum + ((size_t)b * H + h) * D + d) = a;
}

// ---------- out[b][j] = W[j,:] . src[b, (maybe head-sliced)] + bias[j] ----------
// one wave per j, 8 batches per wave
__global__ void k_proj8(const float* __restrict__ src, const float* __restrict__ W,
                        const float* __restrict__ bias, float* __restrict__ out,
                        int bstride, int hstride) {
  const int j = blockIdx.x, lane = threadIdx.x;
  const int h = j >> 6;
  const float4* wr = (const float4*)(W + (size_t)j * D);
  float acc[8];
#pragma unroll
  for (int b = 0; b < 8; b++) acc[b] = 0.f;
#pragma unroll
  for (int k = 0; k < 4; k++) {
    const float4 w4 = wr[lane + 64 * k];
#pragma unroll
    for (int b = 0; b < 8; b++) {
      const float4 s4 =
          ((const float4*)(src + (size_t)b * bstride + (size_t)h * hstride))[lane + 64 * k];
      acc[b] = fmaf(w4.x, s4.x, acc[b]); acc[b] = fmaf(w4.y, s4.y, acc[b]);
      acc[b] = fmaf(w4.z, s4.z, acc[b]); acc[b] = fmaf(w4.w, s4.w, acc[b]);
    }
  }
#pragma unroll
  for (int b = 0; b < 8; b++) acc[b] = wred_sum(acc[b]);
  if (!lane) {
    const float bj = bias[j];
#pragma unroll
    for (int b = 0; b < 8; b++) out[(size_t)b * D + j] = acc[b] + bj;
  }
}

extern "C" void kernel_launch(void* const* d_in, const int* in_sizes, int n_in,
                              void* d_out, int out_size, void* d_ws, size_t ws_size,
                              hipStream_t stream) {
  const float* x = (const float*)d_in[0];
  const float* query = (const float*)d_in[1];
  const float* norm_g = (const float*)d_in[2];
  const float* norm_b = (const float*)d_in[3];
  const float* nq_g = (const float*)d_in[4];
  const float* nq_b = (const float*)d_in[5];
  const float* nk_g = (const float*)d_in[6];
  const float* nk_b = (const float*)d_in[7];
  const float* nv_g = (const float*)d_in[8];
  const float* nv_b = (const float*)d_in[9];
  const float* no_g = (const float*)d_in[10];
  const float* no_b = (const float*)d_in[11];
  const float* Wq = (const float*)d_in[12];
  const float* bq = (const float*)d_in[13];
  const float* Wk = (const float*)d_in[14];
  // d_in[15] = bk: constant per (b,h) in scores -> cancels in softmax, unused
  const float* Wv = (const float*)d_in[16];
  const float* bv = (const float*)d_in[17];
  const float* Wo = (const float*)d_in[18];
  const float* bo = (const float*)d_in[19];

  char* ws = (char*)d_ws;
  float* qn = (float*)(ws + 0);                       // 4 KB
  float* qv = (float*)(ws + 4096);                    // 4 KB
  unsigned short* U = (unsigned short*)(ws + 8192);   // 32 KB
  float* stats = (float*)(ws + 40960);                // 1 MB
  float* sc = (float*)(ws + 1089536);                 // 4 MB (scores -> attn in place)
  float* wsum = (float*)(ws + 5283840);               // 512 KB
  float* av = (float*)(ws + 5808128);                 // 32 KB
  float* yb = (float*)(ws + 5840896);                 // 32 KB
  float* part = (float*)(ws + 5873664);               // B*CH*16*1024*4

  int CH = 64;
  while (CH > 1 && 5873664ull + (size_t)B * CH * H * D * 4 > ws_size) CH >>= 1;
  const int RPC = S / CH;

  k_ln256<<<1, 256, 0, stream>>>(query, nq_g, nq_b, qn);
  k_qproj<<<256, 256, 0, stream>>>(qn, Wq, bq, qv);
  k_uproj<<<64, 256, 0, stream>>>(qv, Wk, U);
  k_scores<<<1024, 256, 0, stream>>>(x, U, norm_g, norm_b, nk_g, nk_b, stats, sc);
  k_softmax<<<128, 256, 0, stream>>>(sc);
  k_accv<<<B * CH, 512, 0, stream>>>(x, stats, sc, norm_g, norm_b, nv_g, nv_b, part,
                                     CH, RPC);
  k_redpart<<<128, 256, 0, stream>>>(part, wsum, CH);
  k_proj8<<<1024, 64, 0, stream>>>(wsum, Wv, bv, av, H * D, D);  // V-proj on pooled
  k_proj8<<<1024, 64, 0, stream>>>(av, Wo, bo, yb, D, 0);        // O-proj
  k_ln256<<<8, 256, 0, stream>>>(yb, no_g, no_b, (float*)d_out);
}